// Round 6
// baseline (414.379 us; speedup 1.0000x reference)
//
#include <hip/hip_runtime.h>
#include <hip/hip_bf16.h>
#include <hip/hip_fp16.h>
#include <math.h>

#define LQ_  2048
#define LK_  2048
#define D_   128
#define B_   16
#define LN_EPS 1e-5f
#define TK_  32
#define NTILE (LK_ / TK_)
#define NBODY (NTILE / 2)

// Pre-converted tile images in workspace:
#define KH_TILE_US 4096          // 32 rows x 128 d fp16 (8192 B)
#define VT_TILE_U  2048          // 128 d x 16 slot uint (8192 B)
#define KH_BYTES   ((size_t)B_ * NTILE * KH_TILE_US * 2)   // 8,388,608
#define VT_OFF     KH_BYTES                                 // 8,388,608
// total ws: 16,777,216 B

// LDS layout (one 72 KB block):
//   [ 0, 32K):  Kh buffers  [set][dbuf] x 8192 B
//   [32K,64K):  Vt buffers  [set][dbuf] x 8192 B
//   [64K,72K):  Ps bands    8 waves x 1024 B
//   epilogue: [0, 37888) reused as o/l exchange (4 regions x 64 lanes x 37 f32)
#define LDS_TOTAL 73728

typedef __attribute__((ext_vector_type(8))) short short8;
typedef __attribute__((ext_vector_type(8))) _Float16 half8;
typedef __attribute__((ext_vector_type(4))) float f32x4;

union FragU { uint4 u4; short8 s8; half8 h8; unsigned int u[4]; };

__device__ __forceinline__ unsigned int pk_bf16(float a, float b) {
  __hip_bfloat162 h = __float22bfloat162_rn(make_float2(a, b));
  unsigned int u;
  __builtin_memcpy(&u, &h, 4);
  return u;
}
__device__ __forceinline__ unsigned short bf16_bits(float x) {
  return (unsigned short)(pk_bf16(x, 0.f) & 0xffffu);
}
__device__ __forceinline__ unsigned int pk_f16(float a, float b) {
  __half2 h = __floats2half2_rn(a, b);
  unsigned int u;
  __builtin_memcpy(&u, &h, 4);
  return u;
}
__device__ __forceinline__ float f16_lo(unsigned int u) {
  unsigned short s = (unsigned short)(u & 0xffffu);
  __half h; __builtin_memcpy(&h, &s, 2); return __half2float(h);
}
__device__ __forceinline__ float f16_hi(unsigned int u) {
  unsigned short s = (unsigned short)(u >> 16);
  __half h; __builtin_memcpy(&h, &s, 2); return __half2float(h);
}

// K tiles: ushort [32 rows][128 d], 16B(8-elem)-chunk XOR swizzle by row.
__device__ __forceinline__ int idxK(int row, int d) {
  return row * 128 + ((((d >> 3) ^ row) & 15) << 3) + (d & 7);
}
// Vt: uint [128 d][16 kp-slots]; 16B chunk g' = (g + (d>>1)) & 3.
__device__ __forceinline__ int idxVt(int d, int kp) {
  return d * 16 + ((((kp >> 2) + (d >> 1)) & 3) << 2) + (kp & 3);
}
// Ps: ushort [128 rows][32 cols] bands; wave w owns rows [w*16, +16).
__device__ __forceinline__ int idxPs(int row, int col) {
  return row * 32 + ((((col >> 3) ^ (row >> 2)) & 3) << 3) + (col & 7);
}

// Barrier that drains this wave's tile-stage DMA (stage ops are the oldest;
// the 8 newest vm ops -- prefetched mask loads -- stay in flight) and all ds.
__device__ __forceinline__ void barrier_stage() {
  asm volatile("s_waitcnt vmcnt(8) lgkmcnt(0)\n\ts_barrier" ::: "memory");
}
// Block barrier draining LDS ops only.
__device__ __forceinline__ void barrier_lds() {
  asm volatile("s_waitcnt lgkmcnt(0)\n\ts_barrier" ::: "memory");
}
// Wave-local fence: Ps writes visible to this wave's own reads. No s_barrier.
__device__ __forceinline__ void fence_lds_local() {
  asm volatile("s_waitcnt lgkmcnt(0)" ::: "memory");
}

__device__ __forceinline__ void gld_lds16(const void* g, void* l) {
  __builtin_amdgcn_global_load_lds((const __attribute__((address_space(1))) void*)g,
                                   (__attribute__((address_space(3))) void*)l, 16, 0, 0);
}

// ---------------- pre-pass: K -> fp16 swizzled, V -> bf16-pair Vt ----------
__global__ __launch_bounds__(256) void conv_kv(
    const float* __restrict__ kg, const float* __restrict__ vg,
    unsigned short* __restrict__ khg, unsigned int* __restrict__ vtg)
{
  __shared__ float Vlt[128 * 33];   // V tile transposed, +1-pad rows
  const int tid = threadIdx.x;
  const int blk = blockIdx.x;          // b*64 + t
  const int b = blk >> 6;
  const int t = blk & 63;

  const float* ks = kg + ((size_t)b * LK_ + t * 32) * D_;
  const float* vs = vg + ((size_t)b * LK_ + t * 32) * D_;
  unsigned short* kh = khg + (size_t)blk * KH_TILE_US;
  unsigned int*   vt = vtg + (size_t)blk * VT_TILE_U;

  // K: 512 (row, 8-chunk) items, 2 per thread; coalesced reads, 16B swizzled writes
#pragma unroll
  for (int it = 0; it < 2; it++) {
    const int item = tid + it * 256;
    const int row = item >> 4;
    const int c8  = item & 15;
    const float* p = ks + row * D_ + c8 * 8;
    float4 x = *(const float4*)(p);
    float4 y = *(const float4*)(p + 4);
    FragU H;
    H.u[0] = pk_f16(x.x, x.y); H.u[1] = pk_f16(x.z, x.w);
    H.u[2] = pk_f16(y.x, y.y); H.u[3] = pk_f16(y.z, y.w);
    *(uint4*)&kh[idxK(row, c8 * 8)] = H.u4;
  }

  // V tile -> LDS transposed (coalesced global reads).
#pragma unroll
  for (int i = 0; i < 4; i++) {
    const int item = tid + i * 256;
    const int r = item >> 5, c4 = item & 31;
    float4 x = *(const float4*)&vs[r * D_ + c4 * 4];
    Vlt[(c4 * 4 + 0) * 33 + r] = x.x;
    Vlt[(c4 * 4 + 1) * 33 + r] = x.y;
    Vlt[(c4 * 4 + 2) * 33 + r] = x.z;
    Vlt[(c4 * 4 + 3) * 33 + r] = x.w;
  }
  __syncthreads();

  // Emit Vt image linearly (coalesced writes); inverse-map slot -> kv pair.
#pragma unroll
  for (int i = 0; i < 8; i++) {
    const int o = tid + i * 256;
    const int d = o >> 4, s = o & 15;
    const int gq = s >> 2, c = s & 3;
    const int kp = (((gq - (d >> 1)) & 3) << 2) | c;
    vt[o] = pk_bf16(Vlt[d * 33 + 2 * kp], Vlt[d * 33 + 2 * kp + 1]);
  }
}

// ---------------- main fused attention + LN ----------------
// Stage one tile's images into LDS via global_load_lds: 4 x 1KiB per wave,
// 4 cooperating waves (wr = 0..3) cover 8 KB K + 8 KB Vt.
__device__ __forceinline__ void stage_tile(int wr, int lane,
    const unsigned short* khT, const unsigned int* vtT,
    int tile, char* khs, char* vts)
{
  const char* gkh = (const char*)(khT + (size_t)tile * KH_TILE_US);
  const char* gvt = (const char*)(vtT + (size_t)tile * VT_TILE_U);
#pragma unroll
  for (int c = 0; c < 2; c++) {
    const int off = (wr + 4 * c) << 10;            // 1 KiB chunks
    gld_lds16(gkh + off + lane * 16, khs + off);
    gld_lds16(gvt + off + lane * 16, vts + off);
  }
}

__global__ __launch_bounds__(512, 4) void attn_ln_mfma(
    const float* __restrict__ qg, const float* __restrict__ maskg,
    const float* __restrict__ gammag, const float* __restrict__ betag,
    const unsigned short* __restrict__ khg, const unsigned int* __restrict__ vtg,
    float* __restrict__ outg)
{
  __shared__ __align__(16) char LB[LDS_TOTAL];   // 72 KB -> 2 blocks/CU

  const int tid  = threadIdx.x;
  const int w    = tid >> 6;     // 0..7
  const int ts   = w >> 2;       // k-parity set: 0 = even tiles, 1 = odd tiles
  const int wr   = w & 3;        // row-wave: q-rows [q0 + wr*16, +16)
  const int lane = tid & 63;
  const int quad = lane >> 4;
  const int lr   = lane & 15;

  // XCD swizzle: blocks on XCD x serve batches {2x,2x+1} -> K/V L2-resident.
  const int id   = blockIdx.x;
  const int xcd  = id & 7;
  const int slot = id >> 3;
  const int b    = xcd * 2 + (slot >> 5);
  const int q0   = (slot & 31) * 64;

  const unsigned short* khT = khg + (size_t)b * NTILE * KH_TILE_US;
  const unsigned int*   vtT = vtg + (size_t)b * NTILE * VT_TILE_U;

  // This set's LDS buffer bases (dbuf chosen per body).
  char* khB0 = LB + (ts * 2 + 0) * 8192;
  char* khB1 = LB + (ts * 2 + 1) * 8192;
  char* vtB0 = LB + 32768 + (ts * 2 + 0) * 8192;
  char* vtB1 = LB + 32768 + (ts * 2 + 1) * 8192;
  unsigned short* Ps = (unsigned short*)(LB + 65536);

  // mask rows for this lane: q0 + wr*16 + quad*4 + reg
  const float* mbase = maskg + (size_t)(q0 + wr * 16 + quad * 4) * LK_ + lr;

  // ---- issue tile(ts) stage DMA + mask(ts) prefetch (fly during Q build) ----
  stage_tile(wr, lane, khT, vtT, ts, khB0, vtB0);
  float mA[2][4], mB[2][4];
#pragma unroll
  for (int ct = 0; ct < 2; ct++)
#pragma unroll
    for (int reg = 0; reg < 4; reg++)
      mA[ct][reg] = mbase[(size_t)reg * LK_ + ts * TK_ + ct * 16];

  // ---- Q fragments (fp16 hi/lo) for this wave's 16 rows; row = wr*16 + lr ----
  half8 qh[4], ql[4];
  {
    const float* qrow = qg + ((size_t)b * LQ_ + q0 + wr * 16 + lr) * D_ + quad * 8;
#pragma unroll
    for (int c = 0; c < 4; c++) {
      float4 x = *(const float4*)(qrow + c * 32);
      float4 y = *(const float4*)(qrow + c * 32 + 4);
      FragU H, L;
      H.u[0] = pk_f16(x.x, x.y); H.u[1] = pk_f16(x.z, x.w);
      H.u[2] = pk_f16(y.x, y.y); H.u[3] = pk_f16(y.z, y.w);
      L.u[0] = pk_f16(x.x - f16_lo(H.u[0]), x.y - f16_hi(H.u[0]));
      L.u[1] = pk_f16(x.z - f16_lo(H.u[1]), x.w - f16_hi(H.u[1]));
      L.u[2] = pk_f16(y.x - f16_lo(H.u[2]), y.y - f16_hi(H.u[2]));
      L.u[3] = pk_f16(y.z - f16_lo(H.u[3]), y.w - f16_hi(H.u[3]));
      qh[c] = H.h8; ql[c] = L.h8;
    }
  }

  float l_part[4] = {0.f, 0.f, 0.f, 0.f};   // row = wr*16 + quad*4 + reg
  f32x4 o[8];                               // [nb]: row = quad*4+reg, d = nb*16+lr
  const f32x4 zf = {0.f, 0.f, 0.f, 0.f};
#pragma unroll
  for (int n = 0; n < 8; n++) o[n] = zf;

  // One tile body: this set processes tile mt = 2*i + ts; cur is a literal.
  // mu holds mask(mt); mask(mt+2) is prefetched into mp (named regs, no
  // copies -> counted vmcnt at use). vmcnt(8) invariant per wave preserved.
  auto body = [&](int i, int cur, float (&mu)[2][4], float (&mp)[2][4])
      __attribute__((always_inline)) -> void {
    const unsigned short* khc = (const unsigned short*)(cur ? khB1 : khB0);
    const unsigned int*   vtc = (const unsigned int*)(cur ? vtB1 : vtB0);
    const int mt = 2 * i + ts;

    // All waves past previous body's LDS reads; this wave's stage(mt) done.
    barrier_stage();

    // ---- issue NEXT tile stage (4 vm) + NEXT mask prefetch (8 vm) ----
    if (i + 1 < NBODY) {
      stage_tile(wr, lane, khT, vtT, mt + 2, cur ? khB0 : khB1, cur ? vtB0 : vtB1);
#pragma unroll
      for (int ct = 0; ct < 2; ct++)
#pragma unroll
        for (int reg = 0; reg < 4; reg++)
          mp[ct][reg] = mbase[(size_t)reg * LK_ + (mt + 2) * TK_ + ct * 16];
    }

    // ---- S = Q K^T (fp16 2-term): 16 rows x full 32 k-cols ----
    f32x4 sH[2], sL[2];
    sH[0] = zf; sH[1] = zf; sL[0] = zf; sL[1] = zf;
#pragma unroll
    for (int c = 0; c < 4; c++) {
#pragma unroll
      for (int ct = 0; ct < 2; ct++) {
        FragU kh;
        kh.u4 = *(const uint4*)&khc[idxK(ct * 16 + lr, c * 32 + quad * 8)];
        sH[ct] = __builtin_amdgcn_mfma_f32_16x16x32_f16(qh[c], kh.h8, sH[ct], 0, 0, 0);
        sL[ct] = __builtin_amdgcn_mfma_f32_16x16x32_f16(ql[c], kh.h8, sL[ct], 0, 0, 0);
      }
    }

    // ---- Bv reads issue early: LDS latency overlaps the exp chain ----
    FragU Bv[8];
#pragma unroll
    for (int nb = 0; nb < 8; nb++)
      Bv[nb].u4 = *(const uint4*)&vtc[idxVt(nb * 16 + lr, quad * 4)];

    // ---- max-free softmax; P -> wave-private Ps band as bf16 ----
#pragma unroll
    for (int ct = 0; ct < 2; ct++)
#pragma unroll
      for (int reg = 0; reg < 4; reg++) {
        float s = sH[ct][reg] + sL[ct][reg];
        float p = __expf(s + mu[ct][reg]);
        l_part[reg] += p;
        Ps[idxPs(w * 16 + quad * 4 + reg, ct * 16 + lr)] = bf16_bits(p);
      }

    // Wave-local: own writes visible to own reads. NO cross-wave barrier.
    fence_lds_local();

    // ---- O += P * V: one A-frag (16 rows x 32 k), 8 MFMAs over d ----
    FragU A;
    A.u4 = *(const uint4*)&Ps[idxPs(w * 16 + lr, quad * 8)];
#pragma unroll
    for (int nb = 0; nb < 8; nb++)
      o[nb] = __builtin_amdgcn_mfma_f32_16x16x32_bf16(A.s8, Bv[nb].s8, o[nb], 0, 0, 0);
  };

  for (int i = 0; i < NBODY; i += 2) {
    body(i,     0, mA, mB);   // consumes mask in mA, prefetches into mB
    body(i + 1, 1, mB, mA);   // consumes mask in mB, prefetches into mA
  }

  // ---- merge the two k-parity partial results (max-free: plain sums) ----
  // Exchange region overlays the K/Vt buffers: per row-wave wr, 64 lanes x 37
  // f32 (stride 37 -> bank stride 5, conflict-free). Set 1 writes, set 0 adds.
  float* exch = (float*)LB + (size_t)wr * 64 * 37 + (size_t)lane * 37;

  barrier_lds();   // everyone past final PV reads of the K/Vt buffers
  if (ts == 1) {
#pragma unroll
    for (int nb = 0; nb < 8; nb++)
#pragma unroll
      for (int reg = 0; reg < 4; reg++)
        exch[nb * 4 + reg] = o[nb][reg];
#pragma unroll
    for (int reg = 0; reg < 4; reg++)
      exch[32 + reg] = l_part[reg];
  }
  barrier_lds();   // odd-set partials visible

  if (ts == 0) {
#pragma unroll
    for (int nb = 0; nb < 8; nb++)
#pragma unroll
      for (int reg = 0; reg < 4; reg++)
        o[nb][reg] += exch[nb * 4 + reg];
#pragma unroll
    for (int reg = 0; reg < 4; reg++)
      l_part[reg] += exch[32 + reg];

    // ---- epilogue: wave-internal softmax-normalize + LayerNorm + store ----
    float inv_l[4];
#pragma unroll
    for (int reg = 0; reg < 4; reg++) {
      float l = l_part[reg];
#pragma unroll
      for (int m = 1; m <= 8; m <<= 1) l += __shfl_xor(l, m, 64);
      inv_l[reg] = 1.f / l;
    }

    float gam[8], bet[8];
#pragma unroll
    for (int nb = 0; nb < 8; nb++) {
      gam[nb] = gammag[nb * 16 + lr];
      bet[nb] = betag[nb * 16 + lr];
    }

#pragma unroll
    for (int reg = 0; reg < 4; reg++) {
      float s1 = 0.f, s2 = 0.f;
#pragma unroll
      for (int nb = 0; nb < 8; nb++) {
        float v = o[nb][reg] * inv_l[reg];
        o[nb][reg] = v;
        s1 += v; s2 += v * v;
      }
#pragma unroll
      for (int m = 1; m <= 8; m <<= 1) {
        s1 += __shfl_xor(s1, m, 64);
        s2 += __shfl_xor(s2, m, 64);
      }
      const float mean = s1 * (1.f / 128.f);
      const float var  = s2 * (1.f / 128.f) - mean * mean;
      const float rstd = rsqrtf(var + LN_EPS);

      float* op = outg + ((size_t)b * LQ_ + q0 + wr * 16 + quad * 4 + reg) * D_ + lr;
#pragma unroll
      for (int nb = 0; nb < 8; nb++)
        op[nb * 16] = (o[nb][reg] - mean) * rstd * gam[nb] + bet[nb];
    }
  }
}

extern "C" void kernel_launch(void* const* d_in, const int* in_sizes, int n_in,
                              void* d_out, int out_size, void* d_ws, size_t ws_size,
                              hipStream_t stream) {
  const float* q     = (const float*)d_in[0];
  const float* k     = (const float*)d_in[1];
  const float* v     = (const float*)d_in[2];
  const float* mask  = (const float*)d_in[3];
  const float* gamma = (const float*)d_in[4];
  const float* beta  = (const float*)d_in[5];
  float* out = (float*)d_out;

  unsigned short* khg = (unsigned short*)d_ws;
  unsigned int*   vtg = (unsigned int*)((char*)d_ws + VT_OFF);

  conv_kv<<<dim3(B_ * NTILE), dim3(256), 0, stream>>>(k, v, khg, vtg);
  attn_ln_mfma<<<dim3(512), dim3(512), 0, stream>>>(q, mask, gamma, beta,
                                                    khg, vtg, out);
}

// Round 7
// 193.554 us; speedup vs baseline: 2.1409x; 2.1409x over previous
//
#include <hip/hip_runtime.h>
#include <hip/hip_bf16.h>
#include <hip/hip_fp16.h>
#include <math.h>

#define LQ_  2048
#define LK_  2048
#define D_   128
#define B_   16
#define LN_EPS 1e-5f
#define TK_  32
#define NTILE (LK_ / TK_)
#define NBODY (NTILE / 2)

// Pre-converted tile images in workspace:
#define KH_TILE_US 4096          // 32 rows x 128 d fp16 (8192 B)
#define VT_TILE_U  2048          // 128 d x 16 slot uint (8192 B)
#define KH_BYTES   ((size_t)B_ * NTILE * KH_TILE_US * 2)   // 8,388,608
#define VT_OFF     KH_BYTES                                 // 8,388,608
// total ws: 16,777,216 B

// LDS layout (one 72 KB block):
//   [ 0, 32K):  Kh buffers  [set][dbuf] x 8192 B
//   [32K,64K):  Vt buffers  [set][dbuf] x 8192 B
//   [64K,72K):  Ps bands    8 waves x 1024 B
//   epilogue: [0, 37888) reused as o/l exchange (4 regions x 64 lanes x 37 f32)
#define LDS_TOTAL 73728

typedef __attribute__((ext_vector_type(8))) short short8;
typedef __attribute__((ext_vector_type(8))) _Float16 half8;
typedef __attribute__((ext_vector_type(4))) float f32x4;

union FragU { uint4 u4; short8 s8; half8 h8; unsigned int u[4]; };

__device__ __forceinline__ unsigned int pk_bf16(float a, float b) {
  __hip_bfloat162 h = __float22bfloat162_rn(make_float2(a, b));
  unsigned int u;
  __builtin_memcpy(&u, &h, 4);
  return u;
}
__device__ __forceinline__ unsigned short bf16_bits(float x) {
  return (unsigned short)(pk_bf16(x, 0.f) & 0xffffu);
}
__device__ __forceinline__ unsigned int pk_f16(float a, float b) {
  __half2 h = __floats2half2_rn(a, b);
  unsigned int u;
  __builtin_memcpy(&u, &h, 4);
  return u;
}
__device__ __forceinline__ float f16_lo(unsigned int u) {
  unsigned short s = (unsigned short)(u & 0xffffu);
  __half h; __builtin_memcpy(&h, &s, 2); return __half2float(h);
}
__device__ __forceinline__ float f16_hi(unsigned int u) {
  unsigned short s = (unsigned short)(u >> 16);
  __half h; __builtin_memcpy(&h, &s, 2); return __half2float(h);
}

// K tiles: ushort [32 rows][128 d], 16B(8-elem)-chunk XOR swizzle by row.
__device__ __forceinline__ int idxK(int row, int d) {
  return row * 128 + ((((d >> 3) ^ row) & 15) << 3) + (d & 7);
}
// Vt: uint [128 d][16 kp-slots]; 16B chunk g' = (g + (d>>1)) & 3.
__device__ __forceinline__ int idxVt(int d, int kp) {
  return d * 16 + ((((kp >> 2) + (d >> 1)) & 3) << 2) + (kp & 3);
}
// Ps: ushort [128 rows][32 cols] bands; wave w owns rows [w*16, +16).
__device__ __forceinline__ int idxPs(int row, int col) {
  return row * 32 + ((((col >> 3) ^ (row >> 2)) & 3) << 3) + (col & 7);
}

// Barrier that drains this wave's tile-stage DMA (stage ops are the oldest;
// the 8 newest vm ops -- prefetched mask loads -- stay in flight) and all ds.
__device__ __forceinline__ void barrier_stage() {
  asm volatile("s_waitcnt vmcnt(8) lgkmcnt(0)\n\ts_barrier" ::: "memory");
}
// Block barrier draining LDS ops only.
__device__ __forceinline__ void barrier_lds() {
  asm volatile("s_waitcnt lgkmcnt(0)\n\ts_barrier" ::: "memory");
}
// Wave-local fence: Ps writes visible to this wave's own reads. No s_barrier.
__device__ __forceinline__ void fence_lds_local() {
  asm volatile("s_waitcnt lgkmcnt(0)" ::: "memory");
}

__device__ __forceinline__ void gld_lds16(const void* g, void* l) {
  __builtin_amdgcn_global_load_lds((const __attribute__((address_space(1))) void*)g,
                                   (__attribute__((address_space(3))) void*)l, 16, 0, 0);
}

// ---------------- pre-pass: K -> fp16 swizzled, V -> bf16-pair Vt ----------
__global__ __launch_bounds__(256) void conv_kv(
    const float* __restrict__ kg, const float* __restrict__ vg,
    unsigned short* __restrict__ khg, unsigned int* __restrict__ vtg)
{
  __shared__ float Vlt[128 * 33];   // V tile transposed, +1-pad rows
  const int tid = threadIdx.x;
  const int blk = blockIdx.x;          // b*64 + t
  const int b = blk >> 6;
  const int t = blk & 63;

  const float* ks = kg + ((size_t)b * LK_ + t * 32) * D_;
  const float* vs = vg + ((size_t)b * LK_ + t * 32) * D_;
  unsigned short* kh = khg + (size_t)blk * KH_TILE_US;
  unsigned int*   vt = vtg + (size_t)blk * VT_TILE_U;

  // K: 512 (row, 8-chunk) items, 2 per thread; coalesced reads, 16B swizzled writes
#pragma unroll
  for (int it = 0; it < 2; it++) {
    const int item = tid + it * 256;
    const int row = item >> 4;
    const int c8  = item & 15;
    const float* p = ks + row * D_ + c8 * 8;
    float4 x = *(const float4*)(p);
    float4 y = *(const float4*)(p + 4);
    FragU H;
    H.u[0] = pk_f16(x.x, x.y); H.u[1] = pk_f16(x.z, x.w);
    H.u[2] = pk_f16(y.x, y.y); H.u[3] = pk_f16(y.z, y.w);
    *(uint4*)&kh[idxK(row, c8 * 8)] = H.u4;
  }

  // V tile -> LDS transposed (coalesced global reads).
#pragma unroll
  for (int i = 0; i < 4; i++) {
    const int item = tid + i * 256;
    const int r = item >> 5, c4 = item & 31;
    float4 x = *(const float4*)&vs[r * D_ + c4 * 4];
    Vlt[(c4 * 4 + 0) * 33 + r] = x.x;
    Vlt[(c4 * 4 + 1) * 33 + r] = x.y;
    Vlt[(c4 * 4 + 2) * 33 + r] = x.z;
    Vlt[(c4 * 4 + 3) * 33 + r] = x.w;
  }
  __syncthreads();

  // Emit Vt image linearly (coalesced writes); inverse-map slot -> kv pair.
#pragma unroll
  for (int i = 0; i < 8; i++) {
    const int o = tid + i * 256;
    const int d = o >> 4, s = o & 15;
    const int gq = s >> 2, c = s & 3;
    const int kp = (((gq - (d >> 1)) & 3) << 2) | c;
    vt[o] = pk_bf16(Vlt[d * 33 + 2 * kp], Vlt[d * 33 + 2 * kp + 1]);
  }
}

// ---------------- main fused attention + LN ----------------
// Stage one tile's images into LDS via global_load_lds: 4 x 1KiB per wave,
// 4 cooperating waves (wr = 0..3) cover 8 KB K + 8 KB Vt.
__device__ __forceinline__ void stage_tile(int wr, int lane,
    const unsigned short* khT, const unsigned int* vtT,
    int tile, char* khs, char* vts)
{
  const char* gkh = (const char*)(khT + (size_t)tile * KH_TILE_US);
  const char* gvt = (const char*)(vtT + (size_t)tile * VT_TILE_U);
#pragma unroll
  for (int c = 0; c < 2; c++) {
    const int off = (wr + 4 * c) << 10;            // 1 KiB chunks
    gld_lds16(gkh + off + lane * 16, khs + off);
    gld_lds16(gvt + off + lane * 16, vts + off);
  }
}

__global__ __launch_bounds__(512, 2) void attn_ln_mfma(
    const float* __restrict__ qg, const float* __restrict__ maskg,
    const float* __restrict__ gammag, const float* __restrict__ betag,
    const unsigned short* __restrict__ khg, const unsigned int* __restrict__ vtg,
    float* __restrict__ outg)
{
  __shared__ __align__(16) char LB[LDS_TOTAL];   // 72 KB -> 2 blocks/CU (LDS-capped)

  const int tid  = threadIdx.x;
  const int w    = tid >> 6;     // 0..7
  const int ts   = w >> 2;       // k-parity set: 0 = even tiles, 1 = odd tiles
  const int wr   = w & 3;        // row-wave: q-rows [q0 + wr*16, +16)
  const int lane = tid & 63;
  const int quad = lane >> 4;
  const int lr   = lane & 15;

  // XCD swizzle: blocks on XCD x serve batches {2x,2x+1} -> K/V L2-resident.
  const int id   = blockIdx.x;
  const int xcd  = id & 7;
  const int slot = id >> 3;
  const int b    = xcd * 2 + (slot >> 5);
  const int q0   = (slot & 31) * 64;

  const unsigned short* khT = khg + (size_t)b * NTILE * KH_TILE_US;
  const unsigned int*   vtT = vtg + (size_t)b * NTILE * VT_TILE_U;

  // This set's LDS buffer bases (dbuf chosen per body).
  char* khB0 = LB + (ts * 2 + 0) * 8192;
  char* khB1 = LB + (ts * 2 + 1) * 8192;
  char* vtB0 = LB + 32768 + (ts * 2 + 0) * 8192;
  char* vtB1 = LB + 32768 + (ts * 2 + 1) * 8192;
  unsigned short* Ps = (unsigned short*)(LB + 65536);

  // mask rows for this lane: q0 + wr*16 + quad*4 + reg
  const float* mbase = maskg + (size_t)(q0 + wr * 16 + quad * 4) * LK_ + lr;

  // ---- issue tile(ts) stage DMA + mask(ts) prefetch (fly during Q build) ----
  stage_tile(wr, lane, khT, vtT, ts, khB0, vtB0);
  float mA[2][4], mB[2][4];
#pragma unroll
  for (int ct = 0; ct < 2; ct++)
#pragma unroll
    for (int reg = 0; reg < 4; reg++)
      mA[ct][reg] = mbase[(size_t)reg * LK_ + ts * TK_ + ct * 16];

  // ---- Q fragments (fp16 hi/lo) for this wave's 16 rows; row = wr*16 + lr ----
  half8 qh[4], ql[4];
  {
    const float* qrow = qg + ((size_t)b * LQ_ + q0 + wr * 16 + lr) * D_ + quad * 8;
#pragma unroll
    for (int c = 0; c < 4; c++) {
      float4 x = *(const float4*)(qrow + c * 32);
      float4 y = *(const float4*)(qrow + c * 32 + 4);
      FragU H, L;
      H.u[0] = pk_f16(x.x, x.y); H.u[1] = pk_f16(x.z, x.w);
      H.u[2] = pk_f16(y.x, y.y); H.u[3] = pk_f16(y.z, y.w);
      L.u[0] = pk_f16(x.x - f16_lo(H.u[0]), x.y - f16_hi(H.u[0]));
      L.u[1] = pk_f16(x.z - f16_lo(H.u[1]), x.w - f16_hi(H.u[1]));
      L.u[2] = pk_f16(y.x - f16_lo(H.u[2]), y.y - f16_hi(H.u[2]));
      L.u[3] = pk_f16(y.z - f16_lo(H.u[3]), y.w - f16_hi(H.u[3]));
      qh[c] = H.h8; ql[c] = L.h8;
    }
  }

  float l_part[4] = {0.f, 0.f, 0.f, 0.f};   // row = wr*16 + quad*4 + reg
  f32x4 o[8];                               // [nb]: row = quad*4+reg, d = nb*16+lr
  const f32x4 zf = {0.f, 0.f, 0.f, 0.f};
#pragma unroll
  for (int n = 0; n < 8; n++) o[n] = zf;

  // One tile body: this set processes tile mt = 2*i + ts; cur is a literal.
  // mu holds mask(mt); mask(mt+2) is prefetched into mp (named regs, no
  // copies -> counted vmcnt at use). vmcnt(8) invariant per wave preserved.
  auto body = [&](int i, int cur, float (&mu)[2][4], float (&mp)[2][4])
      __attribute__((always_inline)) -> void {
    const unsigned short* khc = (const unsigned short*)(cur ? khB1 : khB0);
    const unsigned int*   vtc = (const unsigned int*)(cur ? vtB1 : vtB0);
    const int mt = 2 * i + ts;

    // All waves past previous body's LDS reads; this wave's stage(mt) done.
    barrier_stage();

    // ---- issue NEXT tile stage (4 vm) + NEXT mask prefetch (8 vm) ----
    if (i + 1 < NBODY) {
      stage_tile(wr, lane, khT, vtT, mt + 2, cur ? khB0 : khB1, cur ? vtB0 : vtB1);
#pragma unroll
      for (int ct = 0; ct < 2; ct++)
#pragma unroll
        for (int reg = 0; reg < 4; reg++)
          mp[ct][reg] = mbase[(size_t)reg * LK_ + (mt + 2) * TK_ + ct * 16];
    }

    // ---- S = Q K^T (fp16 2-term): 16 rows x full 32 k-cols ----
    f32x4 sH[2], sL[2];
    sH[0] = zf; sH[1] = zf; sL[0] = zf; sL[1] = zf;
#pragma unroll
    for (int c = 0; c < 4; c++) {
#pragma unroll
      for (int ct = 0; ct < 2; ct++) {
        FragU kh;
        kh.u4 = *(const uint4*)&khc[idxK(ct * 16 + lr, c * 32 + quad * 8)];
        sH[ct] = __builtin_amdgcn_mfma_f32_16x16x32_f16(qh[c], kh.h8, sH[ct], 0, 0, 0);
        sL[ct] = __builtin_amdgcn_mfma_f32_16x16x32_f16(ql[c], kh.h8, sL[ct], 0, 0, 0);
      }
    }

    // ---- Bv reads issue early: LDS latency overlaps the exp chain ----
    FragU Bv[8];
#pragma unroll
    for (int nb = 0; nb < 8; nb++)
      Bv[nb].u4 = *(const uint4*)&vtc[idxVt(nb * 16 + lr, quad * 4)];

    // ---- max-free softmax; P -> wave-private Ps band as bf16 ----
#pragma unroll
    for (int ct = 0; ct < 2; ct++)
#pragma unroll
      for (int reg = 0; reg < 4; reg++) {
        float s = sH[ct][reg] + sL[ct][reg];
        float p = __expf(s + mu[ct][reg]);
        l_part[reg] += p;
        Ps[idxPs(w * 16 + quad * 4 + reg, ct * 16 + lr)] = bf16_bits(p);
      }

    // Wave-local: own writes visible to own reads. NO cross-wave barrier.
    fence_lds_local();

    // ---- O += P * V: one A-frag (16 rows x 32 k), 8 MFMAs over d ----
    FragU A;
    A.u4 = *(const uint4*)&Ps[idxPs(w * 16 + lr, quad * 8)];
#pragma unroll
    for (int nb = 0; nb < 8; nb++)
      o[nb] = __builtin_amdgcn_mfma_f32_16x16x32_bf16(A.s8, Bv[nb].s8, o[nb], 0, 0, 0);
  };

  for (int i = 0; i < NBODY; i += 2) {
    body(i,     0, mA, mB);   // consumes mask in mA, prefetches into mB
    body(i + 1, 1, mB, mA);   // consumes mask in mB, prefetches into mA
  }

  // ---- merge the two k-parity partial results (max-free: plain sums) ----
  // Exchange region overlays the K/Vt buffers: per row-wave wr, 64 lanes x 37
  // f32 (stride 37 -> bank stride 5, conflict-free). Set 1 writes, set 0 adds.
  float* exch = (float*)LB + (size_t)wr * 64 * 37 + (size_t)lane * 37;

  barrier_lds();   // everyone past final PV reads of the K/Vt buffers
  if (ts == 1) {
#pragma unroll
    for (int nb = 0; nb < 8; nb++)
#pragma unroll
      for (int reg = 0; reg < 4; reg++)
        exch[nb * 4 + reg] = o[nb][reg];
#pragma unroll
    for (int reg = 0; reg < 4; reg++)
      exch[32 + reg] = l_part[reg];
  }
  barrier_lds();   // odd-set partials visible

  if (ts == 0) {
#pragma unroll
    for (int nb = 0; nb < 8; nb++)
#pragma unroll
      for (int reg = 0; reg < 4; reg++)
        o[nb][reg] += exch[nb * 4 + reg];
#pragma unroll
    for (int reg = 0; reg < 4; reg++)
      l_part[reg] += exch[32 + reg];

    // ---- epilogue: wave-internal softmax-normalize + LayerNorm + store ----
    float inv_l[4];
#pragma unroll
    for (int reg = 0; reg < 4; reg++) {
      float l = l_part[reg];
#pragma unroll
      for (int m = 1; m <= 8; m <<= 1) l += __shfl_xor(l, m, 64);
      inv_l[reg] = 1.f / l;
    }

    float gam[8], bet[8];
#pragma unroll
    for (int nb = 0; nb < 8; nb++) {
      gam[nb] = gammag[nb * 16 + lr];
      bet[nb] = betag[nb * 16 + lr];
    }

#pragma unroll
    for (int reg = 0; reg < 4; reg++) {
      float s1 = 0.f, s2 = 0.f;
#pragma unroll
      for (int nb = 0; nb < 8; nb++) {
        float v = o[nb][reg] * inv_l[reg];
        o[nb][reg] = v;
        s1 += v; s2 += v * v;
      }
#pragma unroll
      for (int m = 1; m <= 8; m <<= 1) {
        s1 += __shfl_xor(s1, m, 64);
        s2 += __shfl_xor(s2, m, 64);
      }
      const float mean = s1 * (1.f / 128.f);
      const float var  = s2 * (1.f / 128.f) - mean * mean;
      const float rstd = rsqrtf(var + LN_EPS);

      float* op = outg + ((size_t)b * LQ_ + q0 + wr * 16 + quad * 4 + reg) * D_ + lr;
#pragma unroll
      for (int nb = 0; nb < 8; nb++)
        op[nb * 16] = (o[nb][reg] - mean) * rstd * gam[nb] + bet[nb];
    }
  }
}

extern "C" void kernel_launch(void* const* d_in, const int* in_sizes, int n_in,
                              void* d_out, int out_size, void* d_ws, size_t ws_size,
                              hipStream_t stream) {
  const float* q     = (const float*)d_in[0];
  const float* k     = (const float*)d_in[1];
  const float* v     = (const float*)d_in[2];
  const float* mask  = (const float*)d_in[3];
  const float* gamma = (const float*)d_in[4];
  const float* beta  = (const float*)d_in[5];
  float* out = (float*)d_out;

  unsigned short* khg = (unsigned short*)d_ws;
  unsigned int*   vtg = (unsigned int*)((char*)d_ws + VT_OFF);

  conv_kv<<<dim3(B_ * NTILE), dim3(256), 0, stream>>>(k, v, khg, vtg);
  attn_ln_mfma<<<dim3(512), dim3(512), 0, stream>>>(q, mask, gamma, beta,
                                                    khg, vtg, out);
}

// Round 8
// 182.014 us; speedup vs baseline: 2.2766x; 1.0634x over previous
//
#include <hip/hip_runtime.h>
#include <hip/hip_bf16.h>
#include <hip/hip_fp16.h>
#include <math.h>

#define LQ_  2048
#define LK_  2048
#define D_   128
#define B_   16
#define LN_EPS 1e-5f
#define TK_  32
#define NTILE (LK_ / TK_)

// Pre-converted tile images in workspace:
#define KH_TILE_US 4096          // 32 rows x 128 d fp16 (8192 B)
#define VT_TILE_U  2048          // 128 d x 16 slot uint (8192 B)
#define KH_BYTES   ((size_t)B_ * NTILE * KH_TILE_US * 2)   // 8,388,608
#define VT_OFF     KH_BYTES                                 // 8,388,608
// total ws: 16,777,216 B

typedef __attribute__((ext_vector_type(8))) short short8;
typedef __attribute__((ext_vector_type(8))) _Float16 half8;
typedef __attribute__((ext_vector_type(4))) float f32x4;

union FragU { uint4 u4; short8 s8; half8 h8; unsigned int u[4]; };

__device__ __forceinline__ unsigned int pk_bf16(float a, float b) {
  __hip_bfloat162 h = __float22bfloat162_rn(make_float2(a, b));
  unsigned int u;
  __builtin_memcpy(&u, &h, 4);
  return u;
}
__device__ __forceinline__ unsigned int pk_f16(float a, float b) {
  __half2 h = __floats2half2_rn(a, b);
  unsigned int u;
  __builtin_memcpy(&u, &h, 4);
  return u;
}
__device__ __forceinline__ float f16_lo(unsigned int u) {
  unsigned short s = (unsigned short)(u & 0xffffu);
  __half h; __builtin_memcpy(&h, &s, 2); return __half2float(h);
}
__device__ __forceinline__ float f16_hi(unsigned int u) {
  unsigned short s = (unsigned short)(u >> 16);
  __half h; __builtin_memcpy(&h, &s, 2); return __half2float(h);
}

// K tiles: ushort [32 rows][128 d], 16B(8-elem)-chunk XOR swizzle by row.
__device__ __forceinline__ int idxK(int row, int d) {
  return row * 128 + ((((d >> 3) ^ row) & 15) << 3) + (d & 7);
}
// Vt: uint [128 d][16 slots]; 16B chunk rotation p = (g + (d>>1)) & 3.
// Slot->kp mapping is the PV-permuted order (see conv_kv emit): logical
// group g holds kv-pairs {2g, 2g+1, 2g+8, 2g+9} so that the swapped-QK
// in-register P fragment contracts against matching k indices.
__device__ __forceinline__ int idxVt(int d, int slot) {
  return d * 16 + ((((slot >> 2) + (d >> 1)) & 3) << 2) + (slot & 3);
}

// Barrier that drains this wave's tile-stage DMA (stage ops are the oldest;
// the 2 newest vm ops -- prefetched mask float4 loads -- stay in flight).
__device__ __forceinline__ void barrier_stage() {
  asm volatile("s_waitcnt vmcnt(2) lgkmcnt(0)\n\ts_barrier" ::: "memory");
}

__device__ __forceinline__ void gld_lds16(const void* g, void* l) {
  __builtin_amdgcn_global_load_lds((const __attribute__((address_space(1))) void*)g,
                                   (__attribute__((address_space(3))) void*)l, 16, 0, 0);
}

// ---------------- pre-pass: K -> fp16 swizzled, V -> bf16-pair Vt ----------
__global__ __launch_bounds__(256) void conv_kv(
    const float* __restrict__ kg, const float* __restrict__ vg,
    unsigned short* __restrict__ khg, unsigned int* __restrict__ vtg)
{
  __shared__ float Vlt[128 * 33];   // V tile transposed, +1-pad rows
  const int tid = threadIdx.x;
  const int blk = blockIdx.x;          // b*64 + t
  const int b = blk >> 6;
  const int t = blk & 63;

  const float* ks = kg + ((size_t)b * LK_ + t * 32) * D_;
  const float* vs = vg + ((size_t)b * LK_ + t * 32) * D_;
  unsigned short* kh = khg + (size_t)blk * KH_TILE_US;
  unsigned int*   vt = vtg + (size_t)blk * VT_TILE_U;

  // K: 512 (row, 8-chunk) items, 2 per thread; coalesced reads, 16B swizzled writes
#pragma unroll
  for (int it = 0; it < 2; it++) {
    const int item = tid + it * 256;
    const int row = item >> 4;
    const int c8  = item & 15;
    const float* p = ks + row * D_ + c8 * 8;
    float4 x = *(const float4*)(p);
    float4 y = *(const float4*)(p + 4);
    FragU H;
    H.u[0] = pk_f16(x.x, x.y); H.u[1] = pk_f16(x.z, x.w);
    H.u[2] = pk_f16(y.x, y.y); H.u[3] = pk_f16(y.z, y.w);
    *(uint4*)&kh[idxK(row, c8 * 8)] = H.u4;
  }

  // V tile -> LDS transposed (coalesced global reads).
#pragma unroll
  for (int i = 0; i < 4; i++) {
    const int item = tid + i * 256;
    const int r = item >> 5, c4 = item & 31;
    float4 x = *(const float4*)&vs[r * D_ + c4 * 4];
    Vlt[(c4 * 4 + 0) * 33 + r] = x.x;
    Vlt[(c4 * 4 + 1) * 33 + r] = x.y;
    Vlt[(c4 * 4 + 2) * 33 + r] = x.z;
    Vlt[(c4 * 4 + 3) * 33 + r] = x.w;
  }
  __syncthreads();

  // Emit Vt image linearly (coalesced writes); inverse-map phys slot -> kp.
  // Logical slot (g,c) holds kp = 2g + (c>>1)*8 + (c&1); physical group is
  // rotated by (d>>1) for bank spread.
#pragma unroll
  for (int i = 0; i < 8; i++) {
    const int o = tid + i * 256;
    const int d = o >> 4, sp = o & 15;
    const int gl = ((sp >> 2) - (d >> 1)) & 3;
    const int c  = sp & 3;
    const int kp = 2 * gl + ((c >> 1) << 3) + (c & 1);
    vt[o] = pk_bf16(Vlt[d * 33 + 2 * kp], Vlt[d * 33 + 2 * kp + 1]);
  }
}

// ---------------- main fused attention + LN ----------------
// Stage one tile's images into LDS via global_load_lds: 4 x 1KiB per wave,
// 4 cooperating waves cover 8 KB K + 8 KB Vt.
__device__ __forceinline__ void stage_tile(int w, int lane,
    const unsigned short* khT, const unsigned int* vtT,
    int tile, char* khs, char* vts)
{
  const char* gkh = (const char*)(khT + (size_t)tile * KH_TILE_US);
  const char* gvt = (const char*)(vtT + (size_t)tile * VT_TILE_U);
#pragma unroll
  for (int c = 0; c < 2; c++) {
    const int off = (w + 4 * c) << 10;            // 1 KiB chunks
    gld_lds16(gkh + off + lane * 16, khs + off);
    gld_lds16(gvt + off + lane * 16, vts + off);
  }
}

__global__ __launch_bounds__(256, 2) void attn_ln_mfma(
    const float* __restrict__ qg, const float* __restrict__ maskg,
    const float* __restrict__ gammag, const float* __restrict__ betag,
    const unsigned short* __restrict__ khg, const unsigned int* __restrict__ vtg,
    float* __restrict__ outg)
{
  __shared__ unsigned short KhS[2][32 * 128];   // 16 KB (fp16)
  __shared__ unsigned int   VtW[2][128 * 16];   // 16 KB
  // total 32,768 B; no Ps buffer -- P stays in registers (swapped QK).

  const int tid  = threadIdx.x;
  const int w    = tid >> 6;     // wave owns q-rows [q0 + w*16, +16)
  const int lane = tid & 63;
  const int quad = lane >> 4;
  const int lr   = lane & 15;

  // XCD swizzle: blocks on XCD x serve batches {2x,2x+1} -> K/V L2-resident.
  const int id   = blockIdx.x;
  const int xcd  = id & 7;
  const int slot = id >> 3;
  const int b    = xcd * 2 + (slot >> 5);
  const int q0   = (slot & 31) * 64;

  const unsigned short* khT = khg + (size_t)b * NTILE * KH_TILE_US;
  const unsigned int*   vtT = vtg + (size_t)b * NTILE * VT_TILE_U;

  // mask row for this lane's q-row (= lr in swapped layout), quad's k-cols.
  const float* mrow = maskg + (size_t)(q0 + w * 16 + lr) * LK_ + quad * 4;

  // ---- issue tile-0 stage DMA + mask(0) prefetch (fly during Q build) ----
  stage_tile(w, lane, khT, vtT, 0, (char*)&KhS[0][0], (char*)&VtW[0][0]);
  float4 mA[2], mB[2];
  mA[0] = *(const float4*)(mrow);
  mA[1] = *(const float4*)(mrow + 16);

  // ---- Q fragments (fp16 hi/lo) for this wave's 16 rows; row = w*16 + lr ----
  half8 qh[4], ql[4];
  {
    const float* qrow = qg + ((size_t)b * LQ_ + q0 + w * 16 + lr) * D_ + quad * 8;
#pragma unroll
    for (int c = 0; c < 4; c++) {
      float4 x = *(const float4*)(qrow + c * 32);
      float4 y = *(const float4*)(qrow + c * 32 + 4);
      FragU H, L;
      H.u[0] = pk_f16(x.x, x.y); H.u[1] = pk_f16(x.z, x.w);
      H.u[2] = pk_f16(y.x, y.y); H.u[3] = pk_f16(y.z, y.w);
      L.u[0] = pk_f16(x.x - f16_lo(H.u[0]), x.y - f16_hi(H.u[0]));
      L.u[1] = pk_f16(x.z - f16_lo(H.u[1]), x.w - f16_hi(H.u[1]));
      L.u[2] = pk_f16(y.x - f16_lo(H.u[2]), y.y - f16_hi(H.u[2]));
      L.u[3] = pk_f16(y.z - f16_lo(H.u[3]), y.w - f16_hi(H.u[3]));
      qh[c] = H.h8; ql[c] = L.h8;
    }
  }

  float l_part = 0.f;            // sum of p over this lane's k-cols, row = lr
  f32x4 o[8];                    // [nb]: q-row = quad*4+reg, d = nb*16+lr
  const f32x4 zf = {0.f, 0.f, 0.f, 0.f};
#pragma unroll
  for (int n = 0; n < 8; n++) o[n] = zf;

  // One tile body. cur is a literal (0/1); mu holds mask(kt); mask(kt+1) is
  // prefetched into mp (named registers, no copies -> counted vmcnt at use).
  auto body = [&](int kt, int cur, float4 (&mu)[2], float4 (&mp)[2])
      __attribute__((always_inline)) -> void {
    const unsigned short* khc = &KhS[cur][0];
    const unsigned int*   vtc = &VtW[cur][0];

    // All waves past previous tile's LDS reads; this wave's stage(kt) done.
    // The 2 newest vm ops (mask(kt) float4 loads) stay in flight.
    barrier_stage();

    // ---- issue NEXT tile stage (4 vm) + NEXT mask prefetch (2 vm) ----
    if (kt + 1 < NTILE) {
      stage_tile(w, lane, khT, vtT, kt + 1,
                 (char*)&KhS[cur ^ 1][0], (char*)&VtW[cur ^ 1][0]);
      mp[0] = *(const float4*)(mrow + (kt + 1) * TK_);
      mp[1] = *(const float4*)(mrow + (kt + 1) * TK_ + 16);
    }

    // ---- S^T = K Q^T (fp16 2-term, swapped operands: A=K, B=Q) ----
    // sacc[ct] lane layout: k = ct*16 + quad*4 + reg, q-row = lr.
    f32x4 sH[2], sL[2];
    sH[0] = zf; sH[1] = zf; sL[0] = zf; sL[1] = zf;
#pragma unroll
    for (int c = 0; c < 4; c++) {
#pragma unroll
      for (int ct = 0; ct < 2; ct++) {
        FragU kh;
        kh.u4 = *(const uint4*)&khc[idxK(ct * 16 + lr, c * 32 + quad * 8)];
        sH[ct] = __builtin_amdgcn_mfma_f32_16x16x32_f16(kh.h8, qh[c], sH[ct], 0, 0, 0);
        sL[ct] = __builtin_amdgcn_mfma_f32_16x16x32_f16(kh.h8, ql[c], sL[ct], 0, 0, 0);
      }
    }

    // ---- Bv reads issue early: LDS latency overlaps the exp chain ----
    FragU Bv[8];
#pragma unroll
    for (int nb = 0; nb < 8; nb++)
      Bv[nb].u4 = *(const uint4*)&vtc[idxVt(nb * 16 + lr, quad * 4)];

    // ---- max-free softmax, fully in registers ----
    float pv[2][4];
#pragma unroll
    for (int ct = 0; ct < 2; ct++) {
      const float* mf = (const float*)&mu[ct];
#pragma unroll
      for (int reg = 0; reg < 4; reg++) {
        float p = __expf(sH[ct][reg] + sL[ct][reg] + mf[reg]);
        l_part += p;
        pv[ct][reg] = p;
      }
    }

    // ---- pack P -> PV A-fragment in-lane (zero shuffles, zero LDS) ----
    // A slot j (k' = quad*8 + j) carries k = (j>>2)*16 + quad*4 + (j&3);
    // Vt image slots were permuted to match (conv_kv).
    FragU A;
    A.u[0] = pk_bf16(pv[0][0], pv[0][1]);
    A.u[1] = pk_bf16(pv[0][2], pv[0][3]);
    A.u[2] = pk_bf16(pv[1][0], pv[1][1]);
    A.u[3] = pk_bf16(pv[1][2], pv[1][3]);

    // ---- O += P * V: 8 MFMAs over d ----
#pragma unroll
    for (int nb = 0; nb < 8; nb++)
      o[nb] = __builtin_amdgcn_mfma_f32_16x16x32_bf16(A.s8, Bv[nb].s8, o[nb], 0, 0, 0);
  };

  for (int kt = 0; kt < NTILE; kt += 2) {
    body(kt,     0, mA, mB);   // consumes mask in mA, prefetches into mB
    body(kt + 1, 1, mB, mA);   // consumes mask in mB, prefetches into mA
  }

  // ---- epilogue: fully wave-internal ----
  // l total for q-row lr: sum this lane's partial across the 4 quads.
  float lt = l_part;
  lt += __shfl_xor(lt, 16, 64);
  lt += __shfl_xor(lt, 32, 64);
  const float invl = 1.f / lt;           // valid at every lane for row = lr

  // Redistribute: lane needs inv_l for q-rows quad*4+reg (o-layout rows).
  float inv_l[4];
#pragma unroll
  for (int reg = 0; reg < 4; reg++)
    inv_l[reg] = __shfl(invl, quad * 20 + reg, 64);   // lane quad*16 + (quad*4+reg)

  float gam[8], bet[8];
#pragma unroll
  for (int nb = 0; nb < 8; nb++) {
    gam[nb] = gammag[nb * 16 + lr];
    bet[nb] = betag[nb * 16 + lr];
  }

#pragma unroll
  for (int reg = 0; reg < 4; reg++) {
    float s1 = 0.f, s2 = 0.f;
#pragma unroll
    for (int nb = 0; nb < 8; nb++) {
      float v = o[nb][reg] * inv_l[reg];
      o[nb][reg] = v;
      s1 += v; s2 += v * v;
    }
#pragma unroll
    for (int m = 1; m <= 8; m <<= 1) {
      s1 += __shfl_xor(s1, m, 64);
      s2 += __shfl_xor(s2, m, 64);
    }
    const float mean = s1 * (1.f / 128.f);
    const float var  = s2 * (1.f / 128.f) - mean * mean;
    const float rstd = rsqrtf(var + LN_EPS);

    float* op = outg + ((size_t)b * LQ_ + q0 + w * 16 + quad * 4 + reg) * D_ + lr;
#pragma unroll
    for (int nb = 0; nb < 8; nb++)
      op[nb * 16] = (o[nb][reg] - mean) * rstd * gam[nb] + bet[nb];
  }
}

extern "C" void kernel_launch(void* const* d_in, const int* in_sizes, int n_in,
                              void* d_out, int out_size, void* d_ws, size_t ws_size,
                              hipStream_t stream) {
  const float* q     = (const float*)d_in[0];
  const float* k     = (const float*)d_in[1];
  const float* v     = (const float*)d_in[2];
  const float* mask  = (const float*)d_in[3];
  const float* gamma = (const float*)d_in[4];
  const float* beta  = (const float*)d_in[5];
  float* out = (float*)d_out;

  unsigned short* khg = (unsigned short*)d_ws;
  unsigned int*   vtg = (unsigned int*)((char*)d_ws + VT_OFF);

  conv_kv<<<dim3(B_ * NTILE), dim3(256), 0, stream>>>(k, v, khg, vtg);
  attn_ln_mfma<<<dim3(512), dim3(256), 0, stream>>>(q, mask, gamma, beta,
                                                    khg, vtg, out);
}

// Round 9
// 175.236 us; speedup vs baseline: 2.3647x; 1.0387x over previous
//
#include <hip/hip_runtime.h>
#include <hip/hip_bf16.h>
#include <hip/hip_fp16.h>
#include <math.h>

#define LQ_  2048
#define LK_  2048
#define D_   128
#define B_   16
#define LN_EPS 1e-5f
#define TK_  32
#define NTILE (LK_ / TK_)

// Pre-converted tile images in workspace:
#define KH_TILE_US 4096          // 32 rows x 128 d fp16 (8192 B)
#define VT_TILE_U  2048          // 128 d x 16 slot uint (8192 B)
#define KH_BYTES   ((size_t)B_ * NTILE * KH_TILE_US * 2)   // 8,388,608
#define VT_OFF     KH_BYTES                                 // 8,388,608
// total ws: 16,777,216 B

typedef __attribute__((ext_vector_type(8))) short short8;
typedef __attribute__((ext_vector_type(8))) _Float16 half8;
typedef __attribute__((ext_vector_type(4))) float f32x4;

union FragU { uint4 u4; short8 s8; half8 h8; unsigned int u[4]; };

__device__ __forceinline__ unsigned int pk_bf16(float a, float b) {
  __hip_bfloat162 h = __float22bfloat162_rn(make_float2(a, b));
  unsigned int u;
  __builtin_memcpy(&u, &h, 4);
  return u;
}
__device__ __forceinline__ unsigned int pk_f16(float a, float b) {
  __half2 h = __floats2half2_rn(a, b);
  unsigned int u;
  __builtin_memcpy(&u, &h, 4);
  return u;
}
__device__ __forceinline__ float f16_lo(unsigned int u) {
  unsigned short s = (unsigned short)(u & 0xffffu);
  __half h; __builtin_memcpy(&h, &s, 2); return __half2float(h);
}
__device__ __forceinline__ float f16_hi(unsigned int u) {
  unsigned short s = (unsigned short)(u >> 16);
  __half h; __builtin_memcpy(&h, &s, 2); return __half2float(h);
}

// K tiles: ushort [32 rows][128 d], 16B(8-elem)-chunk XOR swizzle by row.
__device__ __forceinline__ int idxK(int row, int d) {
  return row * 128 + ((((d >> 3) ^ row) & 15) << 3) + (d & 7);
}
// Vt: uint [128 d][16 slots]; 16B chunk rotation p = (g + (d>>1)) & 3.
// Slot->kp mapping is the PV-permuted order (see conv_kv emit): logical
// group g holds kv-pairs {2g, 2g+1, 2g+8, 2g+9} so that the swapped-QK
// in-register P fragment contracts against matching k indices.
__device__ __forceinline__ int idxVt(int d, int slot) {
  return d * 16 + ((((slot >> 2) + (d >> 1)) & 3) << 2) + (slot & 3);
}

// Barrier that drains this wave's tile-stage DMA (stage ops are the oldest;
// the 2 newest vm ops -- prefetched mask float4 loads -- stay in flight).
__device__ __forceinline__ void barrier_stage() {
  asm volatile("s_waitcnt vmcnt(2) lgkmcnt(0)\n\ts_barrier" ::: "memory");
}

__device__ __forceinline__ void gld_lds16(const void* g, void* l) {
  __builtin_amdgcn_global_load_lds((const __attribute__((address_space(1))) void*)g,
                                   (__attribute__((address_space(3))) void*)l, 16, 0, 0);
}

// ---------------- pre-pass: K -> fp16 swizzled, V -> bf16-pair Vt ----------
__global__ __launch_bounds__(256) void conv_kv(
    const float* __restrict__ kg, const float* __restrict__ vg,
    unsigned short* __restrict__ khg, unsigned int* __restrict__ vtg)
{
  __shared__ float Vlt[128 * 33];   // V tile transposed, +1-pad rows
  const int tid = threadIdx.x;
  const int blk = blockIdx.x;          // b*64 + t
  const int b = blk >> 6;
  const int t = blk & 63;

  const float* ks = kg + ((size_t)b * LK_ + t * 32) * D_;
  const float* vs = vg + ((size_t)b * LK_ + t * 32) * D_;
  unsigned short* kh = khg + (size_t)blk * KH_TILE_US;
  unsigned int*   vt = vtg + (size_t)blk * VT_TILE_U;

  // K: 512 (row, 8-chunk) items, 2 per thread; coalesced reads, 16B swizzled writes
#pragma unroll
  for (int it = 0; it < 2; it++) {
    const int item = tid + it * 256;
    const int row = item >> 4;
    const int c8  = item & 15;
    const float* p = ks + row * D_ + c8 * 8;
    float4 x = *(const float4*)(p);
    float4 y = *(const float4*)(p + 4);
    FragU H;
    H.u[0] = pk_f16(x.x, x.y); H.u[1] = pk_f16(x.z, x.w);
    H.u[2] = pk_f16(y.x, y.y); H.u[3] = pk_f16(y.z, y.w);
    *(uint4*)&kh[idxK(row, c8 * 8)] = H.u4;
  }

  // V tile -> LDS transposed (coalesced global reads).
#pragma unroll
  for (int i = 0; i < 4; i++) {
    const int item = tid + i * 256;
    const int r = item >> 5, c4 = item & 31;
    float4 x = *(const float4*)&vs[r * D_ + c4 * 4];
    Vlt[(c4 * 4 + 0) * 33 + r] = x.x;
    Vlt[(c4 * 4 + 1) * 33 + r] = x.y;
    Vlt[(c4 * 4 + 2) * 33 + r] = x.z;
    Vlt[(c4 * 4 + 3) * 33 + r] = x.w;
  }
  __syncthreads();

  // Emit Vt image linearly (coalesced writes); inverse-map phys slot -> kp.
  // Logical slot (g,c) holds kp = 2g + (c>>1)*8 + (c&1); physical group is
  // rotated by (d>>1) for bank spread.
#pragma unroll
  for (int i = 0; i < 8; i++) {
    const int o = tid + i * 256;
    const int d = o >> 4, sp = o & 15;
    const int gl = ((sp >> 2) - (d >> 1)) & 3;
    const int c  = sp & 3;
    const int kp = 2 * gl + ((c >> 1) << 3) + (c & 1);
    vt[o] = pk_bf16(Vlt[d * 33 + 2 * kp], Vlt[d * 33 + 2 * kp + 1]);
  }
}

// ---------------- main fused attention + LN ----------------
// Stage one tile's images into LDS via global_load_lds: 4 x 1KiB per wave,
// 4 cooperating waves cover 8 KB K + 8 KB Vt.
__device__ __forceinline__ void stage_tile(int w, int lane,
    const unsigned short* khT, const unsigned int* vtT,
    int tile, char* khs, char* vts)
{
  const char* gkh = (const char*)(khT + (size_t)tile * KH_TILE_US);
  const char* gvt = (const char*)(vtT + (size_t)tile * VT_TILE_U);
#pragma unroll
  for (int c = 0; c < 2; c++) {
    const int off = (w + 4 * c) << 10;            // 1 KiB chunks
    gld_lds16(gkh + off + lane * 16, khs + off);
    gld_lds16(gvt + off + lane * 16, vts + off);
  }
}

__global__ __launch_bounds__(256, 2) void attn_ln_mfma(
    const float* __restrict__ qg, const float* __restrict__ maskg,
    const float* __restrict__ gammag, const float* __restrict__ betag,
    const unsigned short* __restrict__ khg, const unsigned int* __restrict__ vtg,
    float* __restrict__ outg)
{
  __shared__ unsigned short KhS[2][32 * 128];   // 16 KB (fp16)
  __shared__ unsigned int   VtW[2][128 * 16];   // 16 KB
  // total 32,768 B; no Ps buffer -- P stays in registers (swapped QK).

  const int tid  = threadIdx.x;
  const int w    = tid >> 6;     // wave owns q-rows [q0 + w*16, +16)
  const int lane = tid & 63;
  const int quad = lane >> 4;
  const int lr   = lane & 15;

  // XCD swizzle: blocks on XCD x serve batches {2x,2x+1} -> K/V L2-resident.
  const int id   = blockIdx.x;
  const int xcd  = id & 7;
  const int slot = id >> 3;
  const int b    = xcd * 2 + (slot >> 5);
  const int q0   = (slot & 31) * 64;

  const unsigned short* khT = khg + (size_t)b * NTILE * KH_TILE_US;
  const unsigned int*   vtT = vtg + (size_t)b * NTILE * VT_TILE_U;

  // mask row for this lane's q-row (= lr in swapped layout), quad's k-cols.
  const float* mrow = maskg + (size_t)(q0 + w * 16 + lr) * LK_ + quad * 4;

  // ---- issue tile-0 stage DMA + mask(0) prefetch (fly during Q build) ----
  stage_tile(w, lane, khT, vtT, 0, (char*)&KhS[0][0], (char*)&VtW[0][0]);
  float4 mA[2], mB[2];
  mA[0] = *(const float4*)(mrow);
  mA[1] = *(const float4*)(mrow + 16);

  // ---- Q fragments (fp16 hi/lo) for this wave's 16 rows; row = w*16 + lr ----
  half8 qh[4], ql[4];
  {
    const float* qrow = qg + ((size_t)b * LQ_ + q0 + w * 16 + lr) * D_ + quad * 8;
#pragma unroll
    for (int c = 0; c < 4; c++) {
      float4 x = *(const float4*)(qrow + c * 32);
      float4 y = *(const float4*)(qrow + c * 32 + 4);
      FragU H, L;
      H.u[0] = pk_f16(x.x, x.y); H.u[1] = pk_f16(x.z, x.w);
      H.u[2] = pk_f16(y.x, y.y); H.u[3] = pk_f16(y.z, y.w);
      L.u[0] = pk_f16(x.x - f16_lo(H.u[0]), x.y - f16_hi(H.u[0]));
      L.u[1] = pk_f16(x.z - f16_lo(H.u[1]), x.w - f16_hi(H.u[1]));
      L.u[2] = pk_f16(y.x - f16_lo(H.u[2]), y.y - f16_hi(H.u[2]));
      L.u[3] = pk_f16(y.z - f16_lo(H.u[3]), y.w - f16_hi(H.u[3]));
      qh[c] = H.h8; ql[c] = L.h8;
    }
  }

  // ---- loop-invariant swizzled LDS indices (registers, static-indexed) ----
  int kIdx[4][2], vIdx[8];
#pragma unroll
  for (int c = 0; c < 4; c++)
#pragma unroll
    for (int ct = 0; ct < 2; ct++)
      kIdx[c][ct] = idxK(ct * 16 + lr, c * 32 + quad * 8);
#pragma unroll
  for (int nb = 0; nb < 8; nb++)
    vIdx[nb] = idxVt(nb * 16 + lr, quad * 4);

  float l_part = 0.f;            // sum of p over this lane's k-cols, row = lr
  f32x4 o[8];                    // [nb]: q-row = quad*4+reg, d = nb*16+lr
  const f32x4 zf = {0.f, 0.f, 0.f, 0.f};
#pragma unroll
  for (int n = 0; n < 8; n++) o[n] = zf;

  // One tile body. cur is a literal (0/1); mu holds mask(kt); mask(kt+1) is
  // prefetched into mp (named registers, no copies -> counted vmcnt at use).
  auto body = [&](int kt, int cur, float4 (&mu)[2], float4 (&mp)[2])
      __attribute__((always_inline)) -> void {
    const unsigned short* khc = &KhS[cur][0];
    const unsigned int*   vtc = &VtW[cur][0];

    // All waves past previous tile's LDS reads; this wave's stage(kt) done.
    // The 2 newest vm ops (mask(kt) float4 loads) stay in flight.
    barrier_stage();

    // ---- issue NEXT tile stage (4 vm) + NEXT mask prefetch (2 vm) ----
    if (kt + 1 < NTILE) {
      stage_tile(w, lane, khT, vtT, kt + 1,
                 (char*)&KhS[cur ^ 1][0], (char*)&VtW[cur ^ 1][0]);
      mp[0] = *(const float4*)(mrow + (kt + 1) * TK_);
      mp[1] = *(const float4*)(mrow + (kt + 1) * TK_ + 16);
    }

    // ---- burst LDS reads: 8 K frags + 8 Bv frags back-to-back.
    // One wait ramp per tile: first MFMA waits ~one LDS latency while the
    // remaining reads stream; softmax+PV then run register-resident.
    FragU kf[4][2];
#pragma unroll
    for (int c = 0; c < 4; c++)
#pragma unroll
      for (int ct = 0; ct < 2; ct++)
        kf[c][ct].u4 = *(const uint4*)&khc[kIdx[c][ct]];
    FragU Bv[8];
#pragma unroll
    for (int nb = 0; nb < 8; nb++)
      Bv[nb].u4 = *(const uint4*)&vtc[vIdx[nb]];

    // ---- S^T = K Q^T (fp16 2-term, swapped operands: A=K, B=Q) ----
    // sacc[ct] lane layout: k = ct*16 + quad*4 + reg, q-row = lr.
    f32x4 sH[2], sL[2];
    sH[0] = zf; sH[1] = zf; sL[0] = zf; sL[1] = zf;
    __builtin_amdgcn_s_setprio(1);
#pragma unroll
    for (int c = 0; c < 4; c++)
#pragma unroll
      for (int ct = 0; ct < 2; ct++) {
        sH[ct] = __builtin_amdgcn_mfma_f32_16x16x32_f16(kf[c][ct].h8, qh[c], sH[ct], 0, 0, 0);
        sL[ct] = __builtin_amdgcn_mfma_f32_16x16x32_f16(kf[c][ct].h8, ql[c], sL[ct], 0, 0, 0);
      }
    __builtin_amdgcn_s_setprio(0);

    // ---- max-free softmax, fully in registers ----
    float pv[2][4];
#pragma unroll
    for (int ct = 0; ct < 2; ct++) {
      const float* mf = (const float*)&mu[ct];
#pragma unroll
      for (int reg = 0; reg < 4; reg++) {
        float p = __expf(sH[ct][reg] + sL[ct][reg] + mf[reg]);
        l_part += p;
        pv[ct][reg] = p;
      }
    }

    // ---- pack P -> PV A-fragment in-lane (zero shuffles, zero LDS) ----
    // A slot j (k' = quad*8 + j) carries k = (j>>2)*16 + quad*4 + (j&3);
    // Vt image slots were permuted to match (conv_kv).
    FragU A;
    A.u[0] = pk_bf16(pv[0][0], pv[0][1]);
    A.u[1] = pk_bf16(pv[0][2], pv[0][3]);
    A.u[2] = pk_bf16(pv[1][0], pv[1][1]);
    A.u[3] = pk_bf16(pv[1][2], pv[1][3]);

    // ---- O += P * V: 8 independent MFMAs over d ----
    __builtin_amdgcn_s_setprio(1);
#pragma unroll
    for (int nb = 0; nb < 8; nb++)
      o[nb] = __builtin_amdgcn_mfma_f32_16x16x32_bf16(A.s8, Bv[nb].s8, o[nb], 0, 0, 0);
    __builtin_amdgcn_s_setprio(0);
  };

  for (int kt = 0; kt < NTILE; kt += 2) {
    body(kt,     0, mA, mB);   // consumes mask in mA, prefetches into mB
    body(kt + 1, 1, mB, mA);   // consumes mask in mB, prefetches into mA
  }

  // ---- epilogue: fully wave-internal ----
  // l total for q-row lr: sum this lane's partial across the 4 quads.
  float lt = l_part;
  lt += __shfl_xor(lt, 16, 64);
  lt += __shfl_xor(lt, 32, 64);
  const float invl = 1.f / lt;           // valid at every lane for row = lr

  // Redistribute: lane needs inv_l for q-rows quad*4+reg (o-layout rows).
  float inv_l[4];
#pragma unroll
  for (int reg = 0; reg < 4; reg++)
    inv_l[reg] = __shfl(invl, quad * 20 + reg, 64);   // lane quad*16 + (quad*4+reg)

  float gam[8], bet[8];
#pragma unroll
  for (int nb = 0; nb < 8; nb++) {
    gam[nb] = gammag[nb * 16 + lr];
    bet[nb] = betag[nb * 16 + lr];
  }

#pragma unroll
  for (int reg = 0; reg < 4; reg++) {
    float s1 = 0.f, s2 = 0.f;
#pragma unroll
    for (int nb = 0; nb < 8; nb++) {
      float v = o[nb][reg] * inv_l[reg];
      o[nb][reg] = v;
      s1 += v; s2 += v * v;
    }
#pragma unroll
    for (int m = 1; m <= 8; m <<= 1) {
      s1 += __shfl_xor(s1, m, 64);
      s2 += __shfl_xor(s2, m, 64);
    }
    const float mean = s1 * (1.f / 128.f);
    const float var  = s2 * (1.f / 128.f) - mean * mean;
    const float rstd = rsqrtf(var + LN_EPS);

    float* op = outg + ((size_t)b * LQ_ + q0 + w * 16 + quad * 4 + reg) * D_ + lr;
#pragma unroll
    for (int nb = 0; nb < 8; nb++)
      op[nb * 16] = (o[nb][reg] - mean) * rstd * gam[nb] + bet[nb];
  }
}

extern "C" void kernel_launch(void* const* d_in, const int* in_sizes, int n_in,
                              void* d_out, int out_size, void* d_ws, size_t ws_size,
                              hipStream_t stream) {
  const float* q     = (const float*)d_in[0];
  const float* k     = (const float*)d_in[1];
  const float* v     = (const float*)d_in[2];
  const float* mask  = (const float*)d_in[3];
  const float* gamma = (const float*)d_in[4];
  const float* beta  = (const float*)d_in[5];
  float* out = (float*)d_out;

  unsigned short* khg = (unsigned short*)d_ws;
  unsigned int*   vtg = (unsigned int*)((char*)d_ws + VT_OFF);

  conv_kv<<<dim3(B_ * NTILE), dim3(256), 0, stream>>>(k, v, khg, vtg);
  attn_ln_mfma<<<dim3(512), dim3(256), 0, stream>>>(q, mask, gamma, beta,
                                                    khg, vtg, out);
}